// Round 5
// baseline (1192.659 us; speedup 1.0000x reference)
//
#include <hip/hip_runtime.h>
#include <hip/hip_bf16.h>
#include <stdint.h>

typedef unsigned short u16;
typedef unsigned char u8;
typedef float f32x4 __attribute__((ext_vector_type(4)));
typedef float f32x2 __attribute__((ext_vector_type(2)));
typedef _Float16 f16x2 __attribute__((ext_vector_type(2)));
typedef _Float16 f16x8 __attribute__((ext_vector_type(8)));

#define H      300
#define KP     320          // K padded (320 fp8 bytes per row)
#define BATCH  256
#define NX     128
#define NY     128
#define VY     32000
#define NPAD   32768        // vocab padded
#define MROWS  32512        // 127*256 decoder rows

// workspace layout (bytes)
#define OW8_OFF  0UL
#define OW8_BYTES ((unsigned long)NPAD * KP)           // 10,485,760
#define A8_OFF   (OW8_OFF + OW8_BYTES)
#define A8_BYTES ((unsigned long)MROWS * KP)           // 10,403,840
#define WTE_OFF  (A8_OFF + A8_BYTES)
#define WT_BYTES ((unsigned long)H * KP * 4)           // 384,000
#define WTD_OFF  (WTE_OFF + WT_BYTES)
#define SE_OFF   (WTD_OFF + WT_BYTES)
#define SE_BYTES ((unsigned long)MROWS * 4)

typedef const __attribute__((address_space(1))) char* gp_t;
typedef __attribute__((address_space(3))) char* lp_t;

// ---------------- K0: prep (fp8-convert outW padded; transpose enc/dec W) --
__global__ __launch_bounds__(256) void k0_prep(const float* __restrict__ outW,
                                               const float* __restrict__ encW,
                                               const float* __restrict__ decW,
                                               u8* __restrict__ ow8,
                                               float* __restrict__ wte,
                                               float* __restrict__ wtd) {
    long id = (long)blockIdx.x * 256 + threadIdx.x;
    const long n1 = (long)NPAD * KP / 4;         // u32 chunks of OW8
    if (id < n1) {
        int v = (int)(id / 80), k4 = (int)(id % 80) * 4;
        float4 f = {0.f, 0.f, 0.f, 0.f};
        if (v < VY && k4 < H) f = *(const float4*)&outW[(long)v * H + k4]; // k4<=296 -> full
        int w = __builtin_amdgcn_cvt_pk_fp8_f32(f.x, f.y, 0, false);
        w = __builtin_amdgcn_cvt_pk_fp8_f32(f.z, f.w, w, true);
        ((unsigned int*)ow8)[id] = (unsigned int)w;
        return;
    }
    long id2 = id - n1;
    if (id2 < (long)H * KP) {                 // Wt_enc[k][j] = encW[j][k]
        int k = (int)(id2 / KP), j = (int)(id2 % KP);
        wte[id2] = (j < H) ? encW[j * H + k] : 0.f;
        return;
    }
    id2 -= (long)H * KP;
    if (id2 < (long)H * KP) {                 // Wt_dec
        int k = (int)(id2 / KP), j = (int)(id2 % KP);
        wtd[id2] = (j < H) ? decW[j * H + k] : 0.f;
    }
}

// ---------------- K1: register-resident weights, 1 batch elem / block ----
// 256 blocks x 960 threads (15 waves). Thread (s=tid/320, j=tid%320) holds
// W[j][k-slice] as 52 packed fp16 pairs in VGPRs; h is fp16 in LDS (broadcast
// ds_read_b128). Decoder h rows staged to LDS then stored as 80 coalesced u32.
__global__ __launch_bounds__(960, 4) void k1_rnn(const int* __restrict__ x,
                                                 const int* __restrict__ y,
                                                 const float* __restrict__ enc_emb,
                                                 const float* __restrict__ dec_emb,
                                                 const float* __restrict__ encb,
                                                 const float* __restrict__ decb,
                                                 const float* __restrict__ wte,
                                                 const float* __restrict__ wtd,
                                                 u8* __restrict__ A8) {
    const int tid = threadIdx.x;
    const int s = tid / 320;          // 0..2, wave-uniform (320 = 5 waves)
    const int j = tid - s * 320;      // 0..319
    const int b = blockIdx.x;

    __shared__ __align__(16) _Float16 hh[320];   // h (fp16), pad j>=300 = 0
    __shared__ float part[960];
    __shared__ __align__(4) u8 a8row[320];

    for (int i = tid; i < 320; i += 960) hh[i] = (_Float16)0.f;

    const bool comb = (tid < 320);    // s==0 threads do the combine phase
    const float be = (comb && j < H) ? encb[j] : 0.f;
    const float bd = (comb && j < H) ? decb[j] : 0.f;

    // ---- preload encoder weights into registers (fp16 pairs) ----
    f16x2 w[52];
#pragma unroll
    for (int kk = 0; kk < 52; ++kk) {
        int k0 = 2 * (s * 52 + kk);
        float f0 = (k0 < H)     ? wte[k0 * KP + j]       : 0.f;
        float f1 = (k0 + 1 < H) ? wte[(k0 + 1) * KP + j] : 0.f;
        w[kk] = (f16x2){(_Float16)f0, (_Float16)f1};
    }

    // ---- encoder: 128 steps ----
    int idx_n = x[BATCH + b];
    float e_cur = 0.f;
    if (comb && j < H) e_cur = enc_emb[(long)x[b] * H + j];
    __syncthreads();

    const f16x8* hb8 = (const f16x8*)&hh[s * 104];

    for (int t = 0; t < NX; ++t) {
        int idx_n2 = x[min(t + 2, NX - 1) * BATCH + b];
        float e_nx = 0.f;
        if (comb && j < H && t + 1 < NX) e_nx = enc_emb[(long)idx_n * H + j];

        float p0 = 0.f, p1 = 0.f;
#pragma unroll
        for (int i = 0; i < 13; ++i) {
            f16x8 hv = hb8[i];
            f16x2 a0 = {hv[0], hv[1]}, a1 = {hv[2], hv[3]};
            f16x2 a2 = {hv[4], hv[5]}, a3 = {hv[6], hv[7]};
            p0 = __builtin_amdgcn_fdot2(w[4 * i + 0], a0, p0, false);
            p1 = __builtin_amdgcn_fdot2(w[4 * i + 1], a1, p1, false);
            p0 = __builtin_amdgcn_fdot2(w[4 * i + 2], a2, p0, false);
            p1 = __builtin_amdgcn_fdot2(w[4 * i + 3], a3, p1, false);
        }
        part[tid] = p0 + p1;
        __syncthreads();
        if (comb) {
            float v = part[j] + part[320 + j] + part[640 + j] + be + e_cur;
            hh[j] = (_Float16)fmaxf(v, 0.f);
        }
        __syncthreads();
        e_cur = e_nx; idx_n = idx_n2;
    }

    // ---- reload decoder weights ----
#pragma unroll
    for (int kk = 0; kk < 52; ++kk) {
        int k0 = 2 * (s * 52 + kk);
        float f0 = (k0 < H)     ? wtd[k0 * KP + j]       : 0.f;
        float f1 = (k0 + 1 < H) ? wtd[(k0 + 1) * KP + j] : 0.f;
        w[kk] = (f16x2){(_Float16)f0, (_Float16)f1};
    }

    // ---- decoder: 127 steps; write fp8 h rows into A8 (LDS-packed u32) ----
    idx_n = y[BATCH + b];
    e_cur = 0.f;
    if (comb && j < H) e_cur = dec_emb[(long)y[b] * H + j];

    for (int t = 0; t < NY - 1; ++t) {
        int idx_n2 = y[min(t + 2, NY - 1) * BATCH + b];
        float e_nx = 0.f;
        if (comb && j < H && t + 1 < NY - 1) e_nx = dec_emb[(long)idx_n * H + j];

        float p0 = 0.f, p1 = 0.f;
#pragma unroll
        for (int i = 0; i < 13; ++i) {
            f16x8 hv = hb8[i];
            f16x2 a0 = {hv[0], hv[1]}, a1 = {hv[2], hv[3]};
            f16x2 a2 = {hv[4], hv[5]}, a3 = {hv[6], hv[7]};
            p0 = __builtin_amdgcn_fdot2(w[4 * i + 0], a0, p0, false);
            p1 = __builtin_amdgcn_fdot2(w[4 * i + 1], a1, p1, false);
            p0 = __builtin_amdgcn_fdot2(w[4 * i + 2], a2, p0, false);
            p1 = __builtin_amdgcn_fdot2(w[4 * i + 3], a3, p1, false);
        }
        part[tid] = p0 + p1;
        __syncthreads();
        if (comb) {
            float v = part[j] + part[320 + j] + part[640 + j] + bd + e_cur;
            v = fmaxf(v, 0.f);
            hh[j] = (_Float16)v;
            int pk = __builtin_amdgcn_cvt_pk_fp8_f32(v, v, 0, false);
            a8row[j] = (u8)(pk & 0xff);
        }
        __syncthreads();
        if (tid < 80)   // coalesced 320B row store
            ((unsigned int*)(A8 + (long)(t * BATCH + b) * KP))[tid] =
                ((const unsigned int*)a8row)[tid];
        e_cur = e_nx; idx_n = idx_n2;
    }
}

// ---------------- K2: fp8 logits GEMM + exp row-sum ----------------------
// 508 rowblocks (64 rows) x 8 colgroups (cg==XCD slice of outW for L2 hits).
// 4 waves/block, wave = 64 rows x 64 cols. A fragments live in 80 VGPRs
// (loaded once from global); B staged WAVE-PRIVATE via global_load_lds into
// 4 x 2KB slots, 3-iteration runway, gated by manual s_waitcnt vmcnt(6) --
// NO __syncthreads in the K-loop (nothing is shared across waves).
__global__ __launch_bounds__(256, 2) void k2_gemm(const u8* __restrict__ A8,
                                                  const u8* __restrict__ OW8,
                                                  const float* __restrict__ outb,
                                                  float* __restrict__ sumexp) {
    const int tid = threadIdx.x;
    const int lane = tid & 63, wave = tid >> 6;     // wave == col-slice wc
    const int lane16 = lane & 15, quad = lane >> 4;
    const int cg = blockIdx.x & 7;
    const int rb = blockIdx.x >> 3;
    const int colbase = cg * 4096;

    __shared__ u8 Bld[4 * 8192];
    __shared__ float rowsum[64];
    if (tid < 64) rowsum[tid] = 0.f;
    __syncthreads();

    u8* wbuf = &Bld[wave * 8192];

    // ---- A fragments -> registers (64 rows x K=320; same for all 4 waves)
    long a[4][10];
    {
        const u8* abase = A8 + ((long)rb * 64 + lane16) * KP + quad * 8;
#pragma unroll
        for (int rt = 0; rt < 4; ++rt)
#pragma unroll
            for (int ks = 0; ks < 10; ++ks)
                a[rt][ks] = *(const long*)(abase + rt * 16 * KP + ks * 32);
    }

    // wave-private B stage: this wave's 64 cols, one K=32 slice -> 2KB slot
    auto stage = [&](int ct3, int ks3, int slot) {
        int colb = colbase + ct3 * 256 + wave * 64;
        const u8* g0 = OW8 + (long)(colb + (lane >> 1)) * KP + ks3 * 32 + (lane & 1) * 16;
        u8* l0 = wbuf + slot * 2048 + lane * 16;
        __builtin_amdgcn_global_load_lds((gp_t)g0, (lp_t)l0, 16, 0, 0);
        __builtin_amdgcn_global_load_lds((gp_t)(g0 + 32 * KP), (lp_t)(l0 + 1024), 16, 0, 0);
    };

    stage(0, 0, 0); stage(0, 1, 1); stage(0, 2, 2);

    float rsum[16];
#pragma unroll
    for (int i = 0; i < 16; ++i) rsum[i] = 0.f;

    for (int ct = 0; ct < 16; ++ct) {
        f32x4 acc[4][4];
#pragma unroll
        for (int p = 0; p < 4; ++p)
#pragma unroll
            for (int q = 0; q < 4; ++q) acc[p][q] = (f32x4){0.f, 0.f, 0.f, 0.f};

#pragma unroll
        for (int ks = 0; ks < 10; ++ks) {
            // stage 3 iterations ahead (clamped re-stage at tail: slot unused)
            int s_ct = (ks + 3 < 10) ? ct : ct + 1;
            int s_ks = (ks + 3 < 10) ? (ks + 3) : (ks - 7);
            if (s_ct > 15) { s_ct = 15; s_ks = 9; }
            stage(s_ct, s_ks, (ct * 10 + ks + 3) & 3);

            // FIFO drain: <=6 outstanding leaves exactly the 3 newest stages
            __builtin_amdgcn_s_waitcnt(0x0F76);   // vmcnt(6)

            const u8* rb8 = wbuf + ((ct * 10 + ks) & 3) * 2048;
            long bfr[4];
#pragma unroll
            for (int tc = 0; tc < 4; ++tc)
                bfr[tc] = *(const long*)&rb8[(tc * 16 + lane16) * 32 + quad * 8];
#pragma unroll
            for (int rt = 0; rt < 4; ++rt)
#pragma unroll
                for (int tc = 0; tc < 4; ++tc)
                    acc[rt][tc] = __builtin_amdgcn_mfma_f32_16x16x32_fp8_fp8(
                        a[rt][ks], bfr[tc], acc[rt][tc], 0, 0, 0);
        }

        // epilogue for this 256-col tile
        int cb = colbase + ct * 256 + wave * 64;
#pragma unroll
        for (int tc = 0; tc < 4; ++tc) {
            int v = cb + tc * 16 + lane16;
            bool valid = v < VY;
            float ob = valid ? outb[v] : 0.f;
#pragma unroll
            for (int rt = 0; rt < 4; ++rt)
#pragma unroll
                for (int i = 0; i < 4; ++i) {
                    float lg = acc[rt][tc][i] + ob;
                    if (valid) rsum[rt * 4 + i] += __expf(lg);
                }
        }
    }

    // reduce over 16 column-lanes; lane16==0 holds rows quad*4+i per rt
#pragma unroll
    for (int m = 1; m < 16; m <<= 1)
#pragma unroll
        for (int i = 0; i < 16; ++i) rsum[i] += __shfl_xor(rsum[i], m, 64);
    if (lane16 == 0) {
#pragma unroll
        for (int rt = 0; rt < 4; ++rt)
#pragma unroll
            for (int i = 0; i < 4; ++i)
                atomicAdd(&rowsum[rt * 16 + quad * 4 + i], rsum[rt * 4 + i]);
    }
    __syncthreads();
    if (tid < 64) atomicAdd(&sumexp[(long)rb * 64 + tid], rowsum[tid]);
}

// ---------------- K3: target logit + CE + final reduce -------------------
__global__ __launch_bounds__(256) void k3_ce(const u8* __restrict__ A8,
                                             const u8* __restrict__ OW8,
                                             const float* __restrict__ outb,
                                             const float* __restrict__ sumexp,
                                             const int* __restrict__ y,
                                             float* __restrict__ out) {
    const int wave = threadIdx.x >> 6, lane = threadIdx.x & 63;
    const int r = blockIdx.x * 4 + wave;         // 0..32511
    const int t = r >> 8, b = r & 255;
    const int tgt = y[(t + 1) * BATCH + b];
    const unsigned int* ar = (const unsigned int*)(A8 + (long)r * KP);
    const unsigned int* wr_ = (const unsigned int*)(OW8 + (long)tgt * KP);
    float s = 0.f;
#pragma unroll
    for (int i = 0; i < 2; ++i) {
        int c = i * 64 + lane;                   // 80 u32 chunks per row
        if (c < 80) {
            unsigned int a4 = ar[c], w4 = wr_[c];
            f32x2 al = __builtin_amdgcn_cvt_pk_f32_fp8(a4, false);
            f32x2 ah = __builtin_amdgcn_cvt_pk_f32_fp8(a4, true);
            f32x2 wl = __builtin_amdgcn_cvt_pk_f32_fp8(w4, false);
            f32x2 wh = __builtin_amdgcn_cvt_pk_f32_fp8(w4, true);
            s += al[0] * wl[0] + al[1] * wl[1] + ah[0] * wh[0] + ah[1] * wh[1];
        }
    }
#pragma unroll
    for (int m = 1; m < 64; m <<= 1) s += __shfl_xor(s, m, 64);
    __shared__ float part[4];
    if (lane == 0) part[wave] = logf(sumexp[r]) - (s + outb[tgt]);
    __syncthreads();
    if (threadIdx.x == 0) {
        float tot = part[0] + part[1] + part[2] + part[3];
        atomicAdd(out, tot * (1.0f / 256.0f));
    }
}

// ---------------- launch --------------------------------------------------
extern "C" void kernel_launch(void* const* d_in, const int* in_sizes, int n_in,
                              void* d_out, int out_size, void* d_ws, size_t ws_size,
                              hipStream_t stream) {
    (void)in_sizes; (void)n_in; (void)out_size; (void)ws_size;
    const int*   x       = (const int*)d_in[0];
    const int*   y       = (const int*)d_in[1];
    const float* enc_emb = (const float*)d_in[2];
    const float* encW    = (const float*)d_in[3];
    const float* encb    = (const float*)d_in[4];
    const float* dec_emb = (const float*)d_in[5];
    const float* decW    = (const float*)d_in[6];
    const float* decb    = (const float*)d_in[7];
    const float* outW    = (const float*)d_in[8];
    const float* outb    = (const float*)d_in[9];

    char* ws = (char*)d_ws;
    u8* ow8  = (u8*)(ws + OW8_OFF);
    u8* A8   = (u8*)(ws + A8_OFF);
    float* wte    = (float*)(ws + WTE_OFF);
    float* wtd    = (float*)(ws + WTD_OFF);
    float* sumexp = (float*)(ws + SE_OFF);

    hipMemsetAsync(sumexp, 0, SE_BYTES, stream);
    hipMemsetAsync(d_out, 0, sizeof(float), stream);

    long n0 = (long)NPAD * KP / 4 + 2L * H * KP;
    k0_prep<<<(int)((n0 + 255) / 256), 256, 0, stream>>>(outW, encW, decW, ow8, wte, wtd);
    k1_rnn<<<256, 960, 0, stream>>>(x, y, enc_emb, dec_emb, encb, decb, wte, wtd, A8);
    k2_gemm<<<508 * 8, 256, 0, stream>>>(A8, ow8, outb, sumexp);
    k3_ce<<<8128, 256, 0, stream>>>(A8, ow8, outb, sumexp, y, (float*)d_out);
}

// Round 6
// 1038.963 us; speedup vs baseline: 1.1479x; 1.1479x over previous
//
#include <hip/hip_runtime.h>
#include <hip/hip_bf16.h>
#include <stdint.h>

typedef unsigned short u16;
typedef unsigned char u8;
typedef float f32x4 __attribute__((ext_vector_type(4)));
typedef float f32x2 __attribute__((ext_vector_type(2)));
typedef _Float16 f16x2 __attribute__((ext_vector_type(2)));
typedef _Float16 f16x8 __attribute__((ext_vector_type(8)));

#define H      300
#define KP     320          // K padded (320 fp8 bytes per row)
#define BATCH  256
#define NX     128
#define NY     128
#define VY     32000
#define NPAD   32768        // vocab padded
#define MROWS  32512        // 127*256 decoder rows

// Swizzled OW layout (OWS): vocab col v, k -> tile = v>>6 (64 cols x 320 K =
// 20480 B each); within tile: byte = (k>>5)*2048 + ((v>>4)&3)*512 + (v&15)*8
// + ((k>>3)&3)*128 + (k&7).  A wave's MFMA B-fragment read (col c=lane16 in
// 16-col block tc, k = ks*32 + quad*8 + j) is then the contiguous 512B range
// [tile*20480 + ks*2048 + tc*512 + lane*8] -- fully coalesced, no LDS needed.

// workspace layout (bytes)
#define OWS_OFF  0UL
#define OWS_BYTES ((unsigned long)NPAD * KP)           // 10,485,760
#define A8_OFF   (OWS_OFF + OWS_BYTES)
#define A8_BYTES ((unsigned long)MROWS * KP)           // 10,403,840
#define WTE_OFF  (A8_OFF + A8_BYTES)
#define WT_BYTES ((unsigned long)H * KP * 4)           // 384,000
#define WTD_OFF  (WTE_OFF + WT_BYTES)
#define SE_OFF   (WTD_OFF + WT_BYTES)
#define SE_BYTES ((unsigned long)MROWS * 4)

// ---------------- K0: prep (fp8 outW -> swizzled OWS; transpose enc/dec W) --
__global__ __launch_bounds__(256) void k0_prep(const float* __restrict__ outW,
                                               const float* __restrict__ encW,
                                               const float* __restrict__ decW,
                                               u8* __restrict__ ows,
                                               float* __restrict__ wte,
                                               float* __restrict__ wtd) {
    long id = (long)blockIdx.x * 256 + threadIdx.x;
    const long n1 = (long)NPAD * KP / 4;         // u32 chunks
    if (id < n1) {
        int v = (int)(id / 80), k4 = (int)(id % 80) * 4;
        float4 f = {0.f, 0.f, 0.f, 0.f};
        if (v < VY && k4 < H) f = *(const float4*)&outW[(long)v * H + k4]; // k4<=296 -> full
        int w = __builtin_amdgcn_cvt_pk_fp8_f32(f.x, f.y, 0, false);
        w = __builtin_amdgcn_cvt_pk_fp8_f32(f.z, f.w, w, true);
        long dst = (long)(v >> 6) * 20480 + (k4 >> 5) * 2048 + ((v >> 4) & 3) * 512
                 + (v & 15) * 8 + ((k4 >> 3) & 3) * 128 + (k4 & 7);
        *(unsigned int*)(ows + dst) = (unsigned int)w;
        return;
    }
    long id2 = id - n1;
    if (id2 < (long)H * KP) {                 // Wt_enc[k][j] = encW[j][k]
        int k = (int)(id2 / KP), j = (int)(id2 % KP);
        wte[id2] = (j < H) ? encW[j * H + k] : 0.f;
        return;
    }
    id2 -= (long)H * KP;
    if (id2 < (long)H * KP) {                 // Wt_dec
        int k = (int)(id2 / KP), j = (int)(id2 % KP);
        wtd[id2] = (j < H) ? decW[j * H + k] : 0.f;
    }
}

// ---------------- K1: register-resident weights, 1 batch elem / block ----
// 256 blocks x 960 threads (15 waves). Thread (s=tid/320, j=tid%320) holds
// W[j][k-slice] as 52 packed fp16 pairs in VGPRs; h is fp16 in LDS (broadcast
// ds_read_b128). Decoder h rows staged to LDS then stored as 80 coalesced u32.
__global__ __launch_bounds__(960, 4) void k1_rnn(const int* __restrict__ x,
                                                 const int* __restrict__ y,
                                                 const float* __restrict__ enc_emb,
                                                 const float* __restrict__ dec_emb,
                                                 const float* __restrict__ encb,
                                                 const float* __restrict__ decb,
                                                 const float* __restrict__ wte,
                                                 const float* __restrict__ wtd,
                                                 u8* __restrict__ A8) {
    const int tid = threadIdx.x;
    const int s = tid / 320;          // 0..2, wave-uniform (320 = 5 waves)
    const int j = tid - s * 320;      // 0..319
    const int b = blockIdx.x;

    __shared__ __align__(16) _Float16 hh[320];   // h (fp16), pad j>=300 = 0
    __shared__ float part[960];
    __shared__ __align__(4) u8 a8row[320];

    for (int i = tid; i < 320; i += 960) hh[i] = (_Float16)0.f;

    const bool comb = (tid < 320);    // s==0 threads do the combine phase
    const float be = (comb && j < H) ? encb[j] : 0.f;
    const float bd = (comb && j < H) ? decb[j] : 0.f;

    // ---- preload encoder weights into registers (fp16 pairs) ----
    f16x2 w[52];
#pragma unroll
    for (int kk = 0; kk < 52; ++kk) {
        int k0 = 2 * (s * 52 + kk);
        float f0 = (k0 < H)     ? wte[k0 * KP + j]       : 0.f;
        float f1 = (k0 + 1 < H) ? wte[(k0 + 1) * KP + j] : 0.f;
        w[kk] = (f16x2){(_Float16)f0, (_Float16)f1};
    }

    // ---- encoder: 128 steps ----
    int idx_n = x[BATCH + b];
    float e_cur = 0.f;
    if (comb && j < H) e_cur = enc_emb[(long)x[b] * H + j];
    __syncthreads();

    const f16x8* hb8 = (const f16x8*)&hh[s * 104];

    for (int t = 0; t < NX; ++t) {
        int idx_n2 = x[min(t + 2, NX - 1) * BATCH + b];
        float e_nx = 0.f;
        if (comb && j < H && t + 1 < NX) e_nx = enc_emb[(long)idx_n * H + j];

        float p0 = 0.f, p1 = 0.f;
#pragma unroll
        for (int i = 0; i < 13; ++i) {
            f16x8 hv = hb8[i];
            f16x2 a0 = {hv[0], hv[1]}, a1 = {hv[2], hv[3]};
            f16x2 a2 = {hv[4], hv[5]}, a3 = {hv[6], hv[7]};
            p0 = __builtin_amdgcn_fdot2(w[4 * i + 0], a0, p0, false);
            p1 = __builtin_amdgcn_fdot2(w[4 * i + 1], a1, p1, false);
            p0 = __builtin_amdgcn_fdot2(w[4 * i + 2], a2, p0, false);
            p1 = __builtin_amdgcn_fdot2(w[4 * i + 3], a3, p1, false);
        }
        part[tid] = p0 + p1;
        __syncthreads();
        if (comb) {
            float v = part[j] + part[320 + j] + part[640 + j] + be + e_cur;
            hh[j] = (_Float16)fmaxf(v, 0.f);
        }
        __syncthreads();
        e_cur = e_nx; idx_n = idx_n2;
    }

    // ---- reload decoder weights ----
#pragma unroll
    for (int kk = 0; kk < 52; ++kk) {
        int k0 = 2 * (s * 52 + kk);
        float f0 = (k0 < H)     ? wtd[k0 * KP + j]       : 0.f;
        float f1 = (k0 + 1 < H) ? wtd[(k0 + 1) * KP + j] : 0.f;
        w[kk] = (f16x2){(_Float16)f0, (_Float16)f1};
    }

    // ---- decoder: 127 steps; write fp8 h rows into A8 (LDS-packed u32) ----
    idx_n = y[BATCH + b];
    e_cur = 0.f;
    if (comb && j < H) e_cur = dec_emb[(long)y[b] * H + j];

    for (int t = 0; t < NY - 1; ++t) {
        int idx_n2 = y[min(t + 2, NY - 1) * BATCH + b];
        float e_nx = 0.f;
        if (comb && j < H && t + 1 < NY - 1) e_nx = dec_emb[(long)idx_n * H + j];

        float p0 = 0.f, p1 = 0.f;
#pragma unroll
        for (int i = 0; i < 13; ++i) {
            f16x8 hv = hb8[i];
            f16x2 a0 = {hv[0], hv[1]}, a1 = {hv[2], hv[3]};
            f16x2 a2 = {hv[4], hv[5]}, a3 = {hv[6], hv[7]};
            p0 = __builtin_amdgcn_fdot2(w[4 * i + 0], a0, p0, false);
            p1 = __builtin_amdgcn_fdot2(w[4 * i + 1], a1, p1, false);
            p0 = __builtin_amdgcn_fdot2(w[4 * i + 2], a2, p0, false);
            p1 = __builtin_amdgcn_fdot2(w[4 * i + 3], a3, p1, false);
        }
        part[tid] = p0 + p1;
        __syncthreads();
        if (comb) {
            float v = part[j] + part[320 + j] + part[640 + j] + bd + e_cur;
            v = fmaxf(v, 0.f);
            hh[j] = (_Float16)v;
            int pk = __builtin_amdgcn_cvt_pk_fp8_f32(v, v, 0, false);
            a8row[j] = (u8)(pk & 0xff);
        }
        __syncthreads();
        if (tid < 80)   // coalesced 320B row store
            ((unsigned int*)(A8 + (long)(t * BATCH + b) * KP))[tid] =
                ((const unsigned int*)a8row)[tid];
        e_cur = e_nx; idx_n = idx_n2;
    }
}

// ---------------- K2: fp8 logits GEMM + exp row-sum, zero-LDS ------------
// 508 rowblocks (64 rows) x 8 colgroups (cg==XCD slice of OWS for L2 hits).
// 4 waves/block; wave = 64 rows x 64 cols per col-tile. A fragments in 80
// VGPRs (loaded once); B fragments loaded straight from the swizzled OWS as
// coalesced 512B global_load_dwordx2 -- no LDS, no barriers, no bank
// conflicts; compiler schedules vmcnt across the unrolled K-loop.
__global__ __launch_bounds__(256, 2) void k2_gemm(const u8* __restrict__ A8,
                                                  const u8* __restrict__ OWS,
                                                  const float* __restrict__ outb,
                                                  float* __restrict__ sumexp) {
    const int tid = threadIdx.x;
    const int lane = tid & 63, wave = tid >> 6;     // wave == col-slice
    const int lane16 = lane & 15, quad = lane >> 4;
    const int cg = blockIdx.x & 7;
    const int rb = blockIdx.x >> 3;
    const int colbase = cg * 4096;

    __shared__ float rowsum[64];
    if (tid < 64) rowsum[tid] = 0.f;
    __syncthreads();

    // ---- A fragments -> registers (64 rows x K=320; same for all 4 waves)
    long a[4][10];
    {
        const u8* abase = A8 + ((long)rb * 64 + lane16) * KP + quad * 8;
#pragma unroll
        for (int rt = 0; rt < 4; ++rt)
#pragma unroll
            for (int ks = 0; ks < 10; ++ks)
                a[rt][ks] = *(const long*)(abase + rt * 16 * KP + ks * 32);
    }

    // wave's B pointer: tile index = (colbase + ct*256 + wave*64) >> 6
    //                              = cg*64 + ct*4 + wave
    const u8* wb = OWS + (long)(cg * 64 + wave) * 20480 + lane * 8;

    float rsum[16];
#pragma unroll
    for (int i = 0; i < 16; ++i) rsum[i] = 0.f;

    for (int ct = 0; ct < 16; ++ct) {
        const u8* ctp = wb + (long)ct * 4 * 20480;
        f32x4 acc[4][4];
#pragma unroll
        for (int p = 0; p < 4; ++p)
#pragma unroll
            for (int q = 0; q < 4; ++q) acc[p][q] = (f32x4){0.f, 0.f, 0.f, 0.f};

#pragma unroll
        for (int ks = 0; ks < 10; ++ks) {
            const u8* p = ctp + ks * 2048;
            long bfr[4];
#pragma unroll
            for (int tc = 0; tc < 4; ++tc)
                bfr[tc] = *(const long*)(p + tc * 512);
#pragma unroll
            for (int rt = 0; rt < 4; ++rt)
#pragma unroll
                for (int tc = 0; tc < 4; ++tc)
                    acc[rt][tc] = __builtin_amdgcn_mfma_f32_16x16x32_fp8_fp8(
                        a[rt][ks], bfr[tc], acc[rt][tc], 0, 0, 0);
        }

        // epilogue for this 256-col tile
        int cb = colbase + ct * 256 + wave * 64;
#pragma unroll
        for (int tc = 0; tc < 4; ++tc) {
            int v = cb + tc * 16 + lane16;
            bool valid = v < VY;
            float ob = valid ? outb[v] : 0.f;
#pragma unroll
            for (int rt = 0; rt < 4; ++rt)
#pragma unroll
                for (int i = 0; i < 4; ++i) {
                    float lg = acc[rt][tc][i] + ob;
                    if (valid) rsum[rt * 4 + i] += __expf(lg);
                }
        }
    }

    // reduce over 16 column-lanes; lane16==0 holds rows quad*4+i per rt
#pragma unroll
    for (int m = 1; m < 16; m <<= 1)
#pragma unroll
        for (int i = 0; i < 16; ++i) rsum[i] += __shfl_xor(rsum[i], m, 64);
    if (lane16 == 0) {
#pragma unroll
        for (int rt = 0; rt < 4; ++rt)
#pragma unroll
            for (int i = 0; i < 4; ++i)
                atomicAdd(&rowsum[rt * 16 + quad * 4 + i], rsum[rt * 4 + i]);
    }
    __syncthreads();
    if (tid < 64) atomicAdd(&sumexp[(long)rb * 64 + tid], rowsum[tid]);
}

// ---------------- K3: target logit + CE + final reduce -------------------
// W target row read from the swizzled OWS: lane l<40 holds (ks=l>>2,
// quad=l&3) -> u64 at tile(tgt) + ks*2048 + ((tgt>>4)&3)*512 + (tgt&15)*8
// + quad*128, covering k = ks*32 + quad*8 + [0,8).
__global__ __launch_bounds__(256) void k3_ce(const u8* __restrict__ A8,
                                             const u8* __restrict__ OWS,
                                             const float* __restrict__ outb,
                                             const float* __restrict__ sumexp,
                                             const int* __restrict__ y,
                                             float* __restrict__ out) {
    const int wave = threadIdx.x >> 6, lane = threadIdx.x & 63;
    const int r = blockIdx.x * 4 + wave;         // 0..32511
    const int t = r >> 8, b = r & 255;
    const int tgt = y[(t + 1) * BATCH + b];
    float s = 0.f;
    if (lane < 40) {
        unsigned long long av = *(const unsigned long long*)(A8 + (long)r * KP + lane * 8);
        long wdst = (long)(tgt >> 6) * 20480 + (lane >> 2) * 2048
                  + ((tgt >> 4) & 3) * 512 + (tgt & 15) * 8 + (lane & 3) * 128;
        unsigned long long wv = *(const unsigned long long*)(OWS + wdst);
        unsigned int a4 = (unsigned int)av, a4h = (unsigned int)(av >> 32);
        unsigned int w4 = (unsigned int)wv, w4h = (unsigned int)(wv >> 32);
        f32x2 al = __builtin_amdgcn_cvt_pk_f32_fp8(a4, false);
        f32x2 ah = __builtin_amdgcn_cvt_pk_f32_fp8(a4, true);
        f32x2 wl = __builtin_amdgcn_cvt_pk_f32_fp8(w4, false);
        f32x2 wh = __builtin_amdgcn_cvt_pk_f32_fp8(w4, true);
        s += al[0] * wl[0] + al[1] * wl[1] + ah[0] * wh[0] + ah[1] * wh[1];
        al = __builtin_amdgcn_cvt_pk_f32_fp8(a4h, false);
        ah = __builtin_amdgcn_cvt_pk_f32_fp8(a4h, true);
        wl = __builtin_amdgcn_cvt_pk_f32_fp8(w4h, false);
        wh = __builtin_amdgcn_cvt_pk_f32_fp8(w4h, true);
        s += al[0] * wl[0] + al[1] * wl[1] + ah[0] * wh[0] + ah[1] * wh[1];
    }
#pragma unroll
    for (int m = 1; m < 64; m <<= 1) s += __shfl_xor(s, m, 64);
    __shared__ float part[4];
    if (lane == 0) part[wave] = logf(sumexp[r]) - (s + outb[tgt]);
    __syncthreads();
    if (threadIdx.x == 0) {
        float tot = part[0] + part[1] + part[2] + part[3];
        atomicAdd(out, tot * (1.0f / 256.0f));
    }
}

// ---------------- launch --------------------------------------------------
extern "C" void kernel_launch(void* const* d_in, const int* in_sizes, int n_in,
                              void* d_out, int out_size, void* d_ws, size_t ws_size,
                              hipStream_t stream) {
    (void)in_sizes; (void)n_in; (void)out_size; (void)ws_size;
    const int*   x       = (const int*)d_in[0];
    const int*   y       = (const int*)d_in[1];
    const float* enc_emb = (const float*)d_in[2];
    const float* encW    = (const float*)d_in[3];
    const float* encb    = (const float*)d_in[4];
    const float* dec_emb = (const float*)d_in[5];
    const float* decW    = (const float*)d_in[6];
    const float* decb    = (const float*)d_in[7];
    const float* outW    = (const float*)d_in[8];
    const float* outb    = (const float*)d_in[9];

    char* ws = (char*)d_ws;
    u8* ows  = (u8*)(ws + OWS_OFF);
    u8* A8   = (u8*)(ws + A8_OFF);
    float* wte    = (float*)(ws + WTE_OFF);
    float* wtd    = (float*)(ws + WTD_OFF);
    float* sumexp = (float*)(ws + SE_OFF);

    hipMemsetAsync(sumexp, 0, SE_BYTES, stream);
    hipMemsetAsync(d_out, 0, sizeof(float), stream);

    long n0 = (long)NPAD * KP / 4 + 2L * H * KP;
    k0_prep<<<(int)((n0 + 255) / 256), 256, 0, stream>>>(outW, encW, decW, ows, wte, wtd);
    k1_rnn<<<256, 960, 0, stream>>>(x, y, enc_emb, dec_emb, encb, decb, wte, wtd, A8);
    k2_gemm<<<508 * 8, 256, 0, stream>>>(A8, ows, outb, sumexp);
    k3_ce<<<8128, 256, 0, stream>>>(A8, ows, outb, sumexp, y, (float*)d_out);
}